// Round 1
// baseline (2086.470 us; speedup 1.0000x reference)
//
#include <hip/hip_runtime.h>

#define DIM   4096
#define NH    32
#define HD    128
#define BATCH 64
#define SMAX  512
#define PBS   16      // paged block size
#define MBS   32      // blocks per sequence
#define DFF   16384
#define EPS   1e-5f

typedef __attribute__((ext_vector_type(4))) float        v4f;
typedef __attribute__((ext_vector_type(4))) unsigned int v4u;
typedef __attribute__((ext_vector_type(2))) unsigned int v2u;
typedef __attribute__((ext_vector_type(8))) __bf16       bf16x8;

// ---- fp32 -> bf16 (RNE) helpers -------------------------------------------
__device__ inline unsigned pk2(float a, float b) {
    unsigned ua = __float_as_uint(a), ub = __float_as_uint(b);
    ua = (ua + 0x7fffu + ((ua >> 16) & 1u)) >> 16;
    ub = (ub + 0x7fffu + ((ub >> 16) & 1u)) >> 16;
    return ua | (ub << 16);
}
__device__ inline unsigned short f2bf(float a) {
    unsigned ua = __float_as_uint(a);
    return (unsigned short)((ua + 0x7fffu + ((ua >> 16) & 1u)) >> 16);
}
__device__ inline bf16x8 pack8(v4f a, v4f b) {
    v4u u = { pk2(a[0], a[1]), pk2(a[2], a[3]), pk2(b[0], b[1]), pk2(b[2], b[3]) };
    return __builtin_bit_cast(bf16x8, u);
}
__device__ inline bf16x8 lda16(const unsigned short* p) {
    v4u u = *(const v4u*)p;
    return __builtin_bit_cast(bf16x8, u);
}

// ---- RMSNorm (x -> bf16 h) -------------------------------------------------
__global__ __launch_bounds__(256) void rms1_kernel(
    const float* __restrict__ x, const float* __restrict__ g,
    unsigned short* __restrict__ h)
{
    int b = blockIdx.x, t = threadIdx.x;
    const float* xr = x + (size_t)b * DIM;
    v4f xv[4];
    float ss = 0.f;
#pragma unroll
    for (int i = 0; i < 4; i++) {
        xv[i] = *(const v4f*)(xr + (t + i * 256) * 4);
        ss += xv[i][0]*xv[i][0] + xv[i][1]*xv[i][1] + xv[i][2]*xv[i][2] + xv[i][3]*xv[i][3];
    }
    __shared__ float red[4];
    int lane = t & 63, wv = t >> 6;
#pragma unroll
    for (int o = 32; o; o >>= 1) ss += __shfl_down(ss, o, 64);
    if (lane == 0) red[wv] = ss;
    __syncthreads();
    ss = red[0] + red[1] + red[2] + red[3];
    float inv = rsqrtf(ss * (1.0f / DIM) + EPS);
    unsigned short* hr = h + (size_t)b * DIM;
#pragma unroll
    for (int i = 0; i < 4; i++) {
        int idx = (t + i * 256) * 4;
        v4f gv = *(const v4f*)(g + idx);
        v2u o2;
        o2[0] = pk2(xv[i][0] * inv * gv[0], xv[i][1] * inv * gv[1]);
        o2[1] = pk2(xv[i][2] * inv * gv[2], xv[i][3] * inv * gv[3]);
        *(v2u*)(hr + idx) = o2;
    }
}

// ---- fused QKV GEMM: qkv[64][12288] = h1 @ [Wq|Wk|Wv]^T --------------------
__global__ __launch_bounds__(256) void gemm_qkv_kernel(
    const unsigned short* __restrict__ A,   // [64][4096] bf16
    const float* __restrict__ Wq, const float* __restrict__ Wk,
    const float* __restrict__ Wv,
    float* __restrict__ out)                // [64][12288]
{
    const int K = DIM;
    int nbase = blockIdx.x * 32;            // 0..12256
    int mat = nbase >> 12;
    const float* W = (mat == 0) ? Wq : ((mat == 1) ? Wk : Wv);
    int ncol = nbase & (DIM - 1);
    int lane = threadIdx.x & 63, wv = threadIdx.x >> 6;
    int col = lane & 15, quad = lane >> 4;
    int nt = wv & 1, mh = wv >> 1;
    const float* wrow = W + (size_t)(ncol + nt * 16 + col) * K + quad * 8;
    const unsigned short* a0 = A + (size_t)(mh * 32 + col) * K + quad * 8;
    const unsigned short* a1 = a0 + (size_t)16 * K;
    v4f acc0 = {0.f, 0.f, 0.f, 0.f}, acc1 = {0.f, 0.f, 0.f, 0.f};
#pragma unroll 4
    for (int k = 0; k < K; k += 32) {
        v4f w0 = *(const v4f*)(wrow + k);
        v4f w1 = *(const v4f*)(wrow + k + 4);
        bf16x8 bf = pack8(w0, w1);
        acc0 = __builtin_amdgcn_mfma_f32_16x16x32_bf16(lda16(a0 + k), bf, acc0, 0, 0, 0);
        acc1 = __builtin_amdgcn_mfma_f32_16x16x32_bf16(lda16(a1 + k), bf, acc1, 0, 0, 0);
    }
    int nglob = nbase + nt * 16 + col;
    int mbase = mh * 32 + quad * 4;
#pragma unroll
    for (int r = 0; r < 4; r++) {
        out[(size_t)(mbase + r) * 12288 + nglob]      = acc0[r];
        out[(size_t)(mbase + 16 + r) * 12288 + nglob] = acc1[r];
    }
}

// ---- K-split GEMM -> partials [2][64][N] -----------------------------------
__global__ __launch_bounds__(256) void gemm_split_kernel(
    const unsigned short* __restrict__ A,   // [64][K] bf16
    const float* __restrict__ W,            // [N][K]
    float* __restrict__ part,               // [2][64][N]
    int K, int N, int kchunk)
{
    int nbase = blockIdx.x * 32;
    int split = blockIdx.y;
    int ks = split * kchunk;
    int lane = threadIdx.x & 63, wv = threadIdx.x >> 6;
    int col = lane & 15, quad = lane >> 4;
    int nt = wv & 1, mh = wv >> 1;
    int n = nbase + nt * 16 + col;
    const float* wrow = W + (size_t)n * K + quad * 8 + ks;
    const unsigned short* a0 = A + (size_t)(mh * 32 + col) * K + quad * 8 + ks;
    const unsigned short* a1 = a0 + (size_t)16 * K;
    v4f acc0 = {0.f, 0.f, 0.f, 0.f}, acc1 = {0.f, 0.f, 0.f, 0.f};
#pragma unroll 4
    for (int k = 0; k < kchunk; k += 32) {
        v4f w0 = *(const v4f*)(wrow + k);
        v4f w1 = *(const v4f*)(wrow + k + 4);
        bf16x8 bf = pack8(w0, w1);
        acc0 = __builtin_amdgcn_mfma_f32_16x16x32_bf16(lda16(a0 + k), bf, acc0, 0, 0, 0);
        acc1 = __builtin_amdgcn_mfma_f32_16x16x32_bf16(lda16(a1 + k), bf, acc1, 0, 0, 0);
    }
    int mbase = mh * 32 + quad * 4;
    float* po = part + (size_t)split * 64 * N;
#pragma unroll
    for (int r = 0; r < 4; r++) {
        po[(size_t)(mbase + r) * N + n]      = acc0[r];
        po[(size_t)(mbase + 16 + r) * N + n] = acc1[r];
    }
}

// ---- W1/W3 GEMM with fused SiLU-gate -> u bf16 [64][16384] -----------------
__global__ __launch_bounds__(256) void gemm_ffn13_kernel(
    const unsigned short* __restrict__ A,   // h2 [64][4096] bf16
    const float* __restrict__ W1, const float* __restrict__ W3,
    unsigned short* __restrict__ U)         // [64][16384] bf16
{
    const int K = DIM;
    int nbase = blockIdx.x * 32;
    int lane = threadIdx.x & 63, wv = threadIdx.x >> 6;
    int col = lane & 15, quad = lane >> 4;
    int nt = wv & 1, mh = wv >> 1;
    int n = nbase + nt * 16 + col;
    const float* w1r = W1 + (size_t)n * K + quad * 8;
    const float* w3r = W3 + (size_t)n * K + quad * 8;
    const unsigned short* a0 = A + (size_t)(mh * 32 + col) * K + quad * 8;
    const unsigned short* a1 = a0 + (size_t)16 * K;
    v4f acc10 = {0.f,0.f,0.f,0.f}, acc11 = {0.f,0.f,0.f,0.f};
    v4f acc30 = {0.f,0.f,0.f,0.f}, acc31 = {0.f,0.f,0.f,0.f};
#pragma unroll 2
    for (int k = 0; k < K; k += 32) {
        v4f p0 = *(const v4f*)(w1r + k);
        v4f p1 = *(const v4f*)(w1r + k + 4);
        bf16x8 b1 = pack8(p0, p1);
        v4f q0 = *(const v4f*)(w3r + k);
        v4f q1 = *(const v4f*)(w3r + k + 4);
        bf16x8 b3 = pack8(q0, q1);
        bf16x8 af0 = lda16(a0 + k);
        bf16x8 af1 = lda16(a1 + k);
        acc10 = __builtin_amdgcn_mfma_f32_16x16x32_bf16(af0, b1, acc10, 0, 0, 0);
        acc11 = __builtin_amdgcn_mfma_f32_16x16x32_bf16(af1, b1, acc11, 0, 0, 0);
        acc30 = __builtin_amdgcn_mfma_f32_16x16x32_bf16(af0, b3, acc30, 0, 0, 0);
        acc31 = __builtin_amdgcn_mfma_f32_16x16x32_bf16(af1, b3, acc31, 0, 0, 0);
    }
    int mbase = mh * 32 + quad * 4;
#pragma unroll
    for (int r = 0; r < 4; r++) {
        float g0 = acc10[r];
        float u0 = g0 / (1.f + __expf(-g0)) * acc30[r];
        U[(size_t)(mbase + r) * DFF + n] = f2bf(u0);
        float g1v = acc11[r];
        float u1 = g1v / (1.f + __expf(-g1v)) * acc31[r];
        U[(size_t)(mbase + 16 + r) * DFF + n] = f2bf(u1);
    }
}

// ---- paged attention: 1 block per (b,h) ------------------------------------
__global__ __launch_bounds__(256) void attn_kernel(
    const float* __restrict__ qkv,          // [64][12288]: q | k | v
    const float* __restrict__ kheap, const float* __restrict__ vheap,
    const int* __restrict__ btab,           // [64][32]
    const int* __restrict__ ctxl,           // [64]
    const float* __restrict__ scale_p,
    unsigned short* __restrict__ o)         // [64][4096] bf16
{
    int b = blockIdx.x >> 5, h = blockIdx.x & 31;
    int t = threadIdx.x;
    int ctx = ctxl[b];
    float scale = scale_p[0];
    __shared__ float qs[HD];
    __shared__ float ps[SMAX];
    __shared__ float redA[4], redB[4];
    __shared__ float vred[256];
    const float* qrow = qkv + (size_t)b * 12288 + h * HD;
    if (t < HD) qs[t] = qrow[t];
    __syncthreads();
    // phase 1: scores
    float lmax = -1e30f;
    for (int s = t; s < ctx; s += 256) {
        const float* kr;
        if (s == ctx - 1) {
            kr = qkv + (size_t)b * 12288 + DIM + h * HD;   // freshly-computed k
        } else {
            int blk = btab[b * MBS + (s >> 4)];
            kr = kheap + (((size_t)blk * NH + h) * PBS + (s & (PBS - 1))) * HD;
        }
        float dot = 0.f;
#pragma unroll
        for (int d4 = 0; d4 < HD; d4 += 4) {
            v4f kv = *(const v4f*)(kr + d4);
            dot += kv[0]*qs[d4] + kv[1]*qs[d4+1] + kv[2]*qs[d4+2] + kv[3]*qs[d4+3];
        }
        float sc = dot * scale;
        ps[s] = sc;
        lmax = fmaxf(lmax, sc);
    }
    int lane = t & 63, wv = t >> 6;
#pragma unroll
    for (int o2 = 32; o2; o2 >>= 1) lmax = fmaxf(lmax, __shfl_down(lmax, o2, 64));
    if (lane == 0) redA[wv] = lmax;
    __syncthreads();
    float M = fmaxf(fmaxf(redA[0], redA[1]), fmaxf(redA[2], redA[3]));
    float lsum = 0.f;
    for (int s = t; s < ctx; s += 256) {
        float e = __expf(ps[s] - M);
        ps[s] = e;
        lsum += e;
    }
#pragma unroll
    for (int o2 = 32; o2; o2 >>= 1) lsum += __shfl_down(lsum, o2, 64);
    if (lane == 0) redB[wv] = lsum;
    __syncthreads();
    float inv = 1.f / (redB[0] + redB[1] + redB[2] + redB[3]);
    // phase 2: P @ V
    int d = t & (HD - 1);
    int half = t >> 7;
    float acc = 0.f;
    for (int s = half; s < ctx; s += 2) {
        float vv;
        if (s == ctx - 1) {
            vv = qkv[(size_t)b * 12288 + 2 * DIM + h * HD + d];
        } else {
            int blk = btab[b * MBS + (s >> 4)];
            vv = vheap[(((size_t)blk * NH + h) * PBS + (s & (PBS - 1))) * HD + d];
        }
        acc += ps[s] * vv;
    }
    vred[t] = acc;
    __syncthreads();
    if (t < HD) {
        float r = (vred[t] + vred[t + 128]) * inv;
        o[(size_t)b * DIM + h * HD + t] = f2bf(r);
    }
}

// ---- Wo partial reduce + residual + RMSNorm2 -------------------------------
__global__ __launch_bounds__(256) void wo_red_rms2_kernel(
    const float* __restrict__ part,         // [2][64][4096]
    const float* __restrict__ x, const float* __restrict__ g,
    float* __restrict__ x2, unsigned short* __restrict__ h2)
{
    int b = blockIdx.x, t = threadIdx.x;
    v4f xv[4];
    float ss = 0.f;
#pragma unroll
    for (int i = 0; i < 4; i++) {
        int idx = (t + i * 256) * 4;
        v4f p0 = *(const v4f*)(part + (size_t)b * DIM + idx);
        v4f p1 = *(const v4f*)(part + (size_t)(64 + b) * DIM + idx);
        v4f xr = *(const v4f*)(x + (size_t)b * DIM + idx);
        v4f s = p0 + p1 + xr;
        xv[i] = s;
        ss += s[0]*s[0] + s[1]*s[1] + s[2]*s[2] + s[3]*s[3];
        *(v4f*)(x2 + (size_t)b * DIM + idx) = s;
    }
    __shared__ float red[4];
    int lane = t & 63, wv = t >> 6;
#pragma unroll
    for (int o = 32; o; o >>= 1) ss += __shfl_down(ss, o, 64);
    if (lane == 0) red[wv] = ss;
    __syncthreads();
    ss = red[0] + red[1] + red[2] + red[3];
    float inv = rsqrtf(ss * (1.0f / DIM) + EPS);
    unsigned short* hr = h2 + (size_t)b * DIM;
#pragma unroll
    for (int i = 0; i < 4; i++) {
        int idx = (t + i * 256) * 4;
        v4f gv = *(const v4f*)(g + idx);
        v2u o2;
        o2[0] = pk2(xv[i][0] * inv * gv[0], xv[i][1] * inv * gv[1]);
        o2[1] = pk2(xv[i][2] * inv * gv[2], xv[i][3] * inv * gv[3]);
        *(v2u*)(hr + idx) = o2;
    }
}

// ---- W2 partial reduce + final residual -> out -----------------------------
__global__ __launch_bounds__(256) void w2_red_kernel(
    const float* __restrict__ part,         // [2][64][4096]
    const float* __restrict__ x2, float* __restrict__ out)
{
    int b = blockIdx.x, t = threadIdx.x;
#pragma unroll
    for (int i = 0; i < 4; i++) {
        int idx = (t + i * 256) * 4;
        v4f p0 = *(const v4f*)(part + (size_t)b * DIM + idx);
        v4f p1 = *(const v4f*)(part + (size_t)(64 + b) * DIM + idx);
        v4f xr = *(const v4f*)(x2 + (size_t)b * DIM + idx);
        *(v4f*)(out + (size_t)b * DIM + idx) = p0 + p1 + xr;
    }
}

extern "C" void kernel_launch(void* const* d_in, const int* in_sizes, int n_in,
                              void* d_out, int out_size, void* d_ws, size_t ws_size,
                              hipStream_t stream)
{
    const float* x     = (const float*)d_in[0];
    const float* kheap = (const float*)d_in[1];
    const float* vheap = (const float*)d_in[2];
    const int*   btab  = (const int*)d_in[3];
    // d_in[4] = slot_mapping (unused; recomputed from context_lens)
    const int*   ctxl  = (const int*)d_in[5];
    const float* scale = (const float*)d_in[9];
    const float* Wq    = (const float*)d_in[13];
    const float* Wk    = (const float*)d_in[14];
    const float* Wv    = (const float*)d_in[15];
    const float* Wo    = (const float*)d_in[16];
    const float* W1    = (const float*)d_in[17];
    const float* W2    = (const float*)d_in[18];
    const float* W3    = (const float*)d_in[19];
    const float* g1    = (const float*)d_in[20];
    const float* g2    = (const float*)d_in[21];
    float* out = (float*)d_out;

    char* w = (char*)d_ws;
    unsigned short* h1   = (unsigned short*)(w);                      // 512 KB
    float*          qkv  = (float*)(w + (512u << 10));                // 3 MB
    unsigned short* obuf = (unsigned short*)(w + (3584u << 10));      // 512 KB
    float*          part = (float*)(w + (4096u << 10));               // 2 MB
    float*          x2   = (float*)(w + (6144u << 10));               // 1 MB
    unsigned short* h2   = (unsigned short*)(w + (7168u << 10));      // 512 KB
    unsigned short* u    = (unsigned short*)(w + (7680u << 10));      // 2 MB

    rms1_kernel<<<64, 256, 0, stream>>>(x, g1, h1);
    gemm_qkv_kernel<<<384, 256, 0, stream>>>(h1, Wq, Wk, Wv, qkv);
    attn_kernel<<<2048, 256, 0, stream>>>(qkv, kheap, vheap, btab, ctxl, scale, obuf);
    gemm_split_kernel<<<dim3(128, 2), 256, 0, stream>>>(obuf, Wo, part, 4096, 4096, 2048);
    wo_red_rms2_kernel<<<64, 256, 0, stream>>>(part, x, g2, x2, h2);
    gemm_ffn13_kernel<<<512, 256, 0, stream>>>(h2, W1, W3, u);
    gemm_split_kernel<<<dim3(128, 2), 256, 0, stream>>>(u, W2, part, 16384, 4096, 8192);
    w2_red_kernel<<<64, 256, 0, stream>>>(part, x2, out);
}